// Round 4
// baseline (2864.460 us; speedup 1.0000x reference)
//
#include <hip/hip_runtime.h>

#define B 8
#define N 16384
#define C_IN 32
#define P 1024

// ---------------------------------------------------------------------------
// FPS: one block per batch, 1024 threads, 16 points/thread.
// R4: R3 proved the data path (global/scratch/LDS all ~2.1us/iter) was never
// the bottleneck -> serial latency chain is. This round:
//  - LDS reads batched 8-at-a-time (8x ds_read_b64, one wait, then compute)
//  - DPP argmax reduces (VALU cross-lane, ~4cyc) replace ds_swizzle shuffles
//  - winner's z carried through the reduce -> no dependent global cz load
//  - centroid captured in regs (thread t keeps iter t), stored once at end
//    -> loop has ZERO VMEM, barrier drains lgkm only.
// x,y in LDS (float2, lane-stride 8B = 2-way bank alias = free), z+dmin regs.
// Bitwise-matches numpy: d = ((dx*dx + dy*dy) + dz*dz), no fma; argmax
// first-idx (within thread: strict > on ascending n; cross-lane: val desc,
// idx asc total order -> unique winner, order-independent).
// ---------------------------------------------------------------------------
#define R16(OP) OP(0) OP(1) OP(2) OP(3) OP(4) OP(5) OP(6) OP(7) \
                OP(8) OP(9) OP(10) OP(11) OP(12) OP(13) OP(14) OP(15)
#define R8A(OP) OP(0) OP(1) OP(2) OP(3) OP(4) OP(5) OP(6) OP(7)
#define R8B(OP) OP(8) OP(9) OP(10) OP(11) OP(12) OP(13) OP(14) OP(15)

// DPP-combine one reduce level of the (val, idx, z) argmax.
// CTRL: 0xB1 quad_perm xor1, 0x4E quad_perm xor2, 0x141 row_half_mirror,
// 0x140 row_mirror, 0x142 row_bcast15, 0x143 row_bcast31.
// update_dpp(old=own) -> lanes without a source keep own value; combine is
// idempotent (ov==v && oi==idx -> keep), so partial-coverage levels are safe.
template <int CTRL>
__device__ __forceinline__ void dpp_combine(float& v, int& idx, float& z) {
  float ov = __int_as_float(__builtin_amdgcn_update_dpp(
      __float_as_int(v), __float_as_int(v), CTRL, 0xF, 0xF, false));
  int oi = __builtin_amdgcn_update_dpp(idx, idx, CTRL, 0xF, 0xF, false);
  float oz = __int_as_float(__builtin_amdgcn_update_dpp(
      __float_as_int(z), __float_as_int(z), CTRL, 0xF, 0xF, false));
  bool better = (ov > v) || (ov == v && oi < idx);
  v   = better ? ov : v;
  idx = better ? oi : idx;
  z   = better ? oz : z;
}

__global__ __launch_bounds__(1024)
void fps_kernel(const float* __restrict__ xyz, float* __restrict__ new_xyz)
{
  __shared__ float2 sxy[N];        // 128 KiB: x,y of every point
  __shared__ float4 rq[2][16];     // per-wave (val, idx-bits, z, pad)

  const int b = blockIdx.x;
  const int t = threadIdx.x;
  const float* xb = xyz + (size_t)b * (N * 3);

#define FPS_DECL(i) float pz##i, dm##i = 1e10f;
  R16(FPS_DECL)
#define FPS_LOAD(i) { const int n = t + (i << 10);                             \
    float x = xb[n * 3 + 0];                                                   \
    float y = xb[n * 3 + 1];                                                   \
    pz##i   = xb[n * 3 + 2];                                                   \
    asm volatile("" : "+v"(pz##i));  /* keep z in a VGPR, no remat/reload */   \
    sxy[n] = make_float2(x, y); }
  R16(FPS_LOAD)

  float cz = xb[2];                // z of point 0 (once, off critical path)
  __syncthreads();
  float2 c0 = sxy[0];
  float cx = c0.x, cy = c0.y;
  float mx = 0.f, my = 0.f, mz = 0.f;   // this thread's captured centroid

  for (int iter = 0; iter < P; ++iter) {
    // thread `iter` captures the centroid; all stores happen after the loop
    bool keep = (t == iter);
    mx = keep ? cx : mx;
    my = keep ? cy : my;
    mz = keep ? cz : mz;
    if (iter == P - 1) break;

    float bestv = -1.0f;
    int   bi = 0;
    float bz = pz0;
    // batched LDS reads: 8 named temps -> 8 ds_read_b64 then compute
#define FPS_PRE(i) float2 q##i = sxy[t + (i << 10)];
#define FPS_CALC(i) {                                                          \
    float dx = __fsub_rn(q##i.x, cx);                                          \
    float dy = __fsub_rn(q##i.y, cy);                                          \
    float dz = __fsub_rn(pz##i, cz);                                           \
    float d  = __fadd_rn(__fadd_rn(__fmul_rn(dx, dx), __fmul_rn(dy, dy)),      \
                         __fmul_rn(dz, dz));                                   \
    dm##i = fminf(dm##i, d);                                                   \
    bool better = dm##i > bestv;                                               \
    bestv = better ? dm##i : bestv;                                            \
    bi    = better ? i      : bi;                                              \
    bz    = better ? pz##i  : bz; }
    { R8A(FPS_PRE) R8A(FPS_CALC) }
    { R8B(FPS_PRE) R8B(FPS_CALC) }
    int besti = t + (bi << 10);

    // 6-level DPP wave argmax (val desc, idx asc); full answer in lane 63
    dpp_combine<0xB1>(bestv, besti, bz);   // xor 1
    dpp_combine<0x4E>(bestv, besti, bz);   // xor 2
    dpp_combine<0x141>(bestv, besti, bz);  // xor 4 (row_half_mirror)
    dpp_combine<0x140>(bestv, besti, bz);  // xor 8 (row_mirror)
    dpp_combine<0x142>(bestv, besti, bz);  // row_bcast15: rows 0->1, 2->3
    dpp_combine<0x143>(bestv, besti, bz);  // row_bcast31: lanes 32-63

    const int par = iter & 1;
    if ((t & 63) == 63)
      rq[par][t >> 6] = make_float4(bestv, __int_as_float(besti), bz, 0.f);
    __syncthreads();

    // cross-wave: 16 values, 4-level DPP reduce within each 16-lane group
    float4 st = rq[par][t & 15];
    float gv = st.x;
    int   gi = __float_as_int(st.y);
    float gz = st.z;
    dpp_combine<0xB1>(gv, gi, gz);
    dpp_combine<0x4E>(gv, gi, gz);
    dpp_combine<0x141>(gv, gi, gz);
    dpp_combine<0x140>(gv, gi, gz);
    // unique winner -> identical result in every lane
    int sel = __builtin_amdgcn_readfirstlane(gi);
    cz = gz;                        // carried z: same bits as xb[sel*3+2]
    float2 nxy = sxy[sel];          // uniform addr -> LDS broadcast
    cx = nxy.x;
    cy = nxy.y;
  }

  // one coalesced-ish store per thread: thread t holds centroid of iter t
  {
    size_t o = ((size_t)b * P + t) * 3;
    new_xyz[o + 0] = mx;
    new_xyz[o + 1] = my;
    new_xyz[o + 2] = mz;
  }
#undef FPS_DECL
#undef FPS_LOAD
#undef FPS_PRE
#undef FPS_CALC
}

// ---------------------------------------------------------------------------
// Ball query, both radii in one pass. One wave per (b,p). Reproduces the
// reference's gemm-form dist2 bitwise: (qq + xx) - 2*((cx*x+cy*y)+cz*z).
// First-nsample-in-index-order via ballot + prefix popcount; pad = first hit.
// ---------------------------------------------------------------------------
__global__ __launch_bounds__(256) void ballq_kernel(
    const float* __restrict__ xyz, const float* __restrict__ new_xyz,
    int* __restrict__ idx0, int* __restrict__ idx1)
{
  const int wid  = blockIdx.x * 4 + (threadIdx.x >> 6);
  const int lane = threadIdx.x & 63;
  const int b = wid >> 10;
  const int p = wid & (P - 1);
  const float* xb = xyz + (size_t)b * (N * 3);
  const size_t bp = (size_t)b * P + p;
  const float cx = new_xyz[bp * 3 + 0];
  const float cy = new_xyz[bp * 3 + 1];
  const float cz = new_xyz[bp * 3 + 2];
  const float qv = __fadd_rn(__fadd_rn(__fmul_rn(cx, cx), __fmul_rn(cy, cy)),
                             __fmul_rn(cz, cz));
  int* __restrict__ o0 = idx0 + bp * 16;
  int* __restrict__ o1 = idx1 + bp * 32;

  int c0 = 0, c1 = 0, f0 = 0, f1 = 0;
  const unsigned long long below = (1ull << lane) - 1ull;

  for (int base = 0; base < N; base += 64) {
    int n = base + lane;
    float x = xb[n * 3 + 0], y = xb[n * 3 + 1], z = xb[n * 3 + 2];
    float xxv = __fadd_rn(__fadd_rn(__fmul_rn(x, x), __fmul_rn(y, y)),
                          __fmul_rn(z, z));
    float dot = __fadd_rn(__fadd_rn(__fmul_rn(cx, x), __fmul_rn(cy, y)),
                          __fmul_rn(cz, z));
    float d2 = __fsub_rn(__fadd_rn(qv, xxv), __fmul_rn(2.0f, dot));
    unsigned long long m0 = __ballot(d2 < 0.25f);
    unsigned long long m1 = __ballot(d2 < 1.0f);
    if (c0 == 0 && m0) f0 = base + __builtin_ctzll(m0);
    if (c1 == 0 && m1) f1 = base + __builtin_ctzll(m1);
    if ((m0 >> lane) & 1ull) {
      int pos = c0 + (int)__builtin_popcountll(m0 & below);
      if (pos < 16) o0[pos] = n;
    }
    if ((m1 >> lane) & 1ull) {
      int pos = c1 + (int)__builtin_popcountll(m1 & below);
      if (pos < 32) o1[pos] = n;
    }
    c0 = min(16, c0 + (int)__builtin_popcountll(m0));
    c1 = min(32, c1 + (int)__builtin_popcountll(m1));
    if (c0 >= 16 && c1 >= 32) break;
  }
  for (int s = c0 + lane; s < 16; s += 64) o0[s] = f0;
  for (int s = c1 + lane; s < 32; s += 64) o1[s] = f1;
}

// ---------------------------------------------------------------------------
// Fused grouping + conv1(+BN+ReLU) + conv2(+BN+ReLU) + max over samples.
// Block = 256 threads handles 8 points; weights staged in LDS once per block.
// out layout: (B, 192, P) at d_out + B*P*3, branch writes CH_OFF..CH_OFF+C2.
// ---------------------------------------------------------------------------
template <int S, int C1, int C2, int CH_OFF>
__global__ __launch_bounds__(256) void mlp_kernel(
    const float* __restrict__ xyz, const float* __restrict__ feats,
    const float* __restrict__ new_xyz, const int* __restrict__ idx,
    const float* __restrict__ w1, const float* __restrict__ s1,
    const float* __restrict__ b1, const float* __restrict__ w2,
    const float* __restrict__ s2, const float* __restrict__ b2,
    float* __restrict__ out)
{
  static_assert((C1 * S) % 256 == 0 && (C2 * S) % 256 == 0, "mapping");
  __shared__ float wl1[35][C1];     // wl1[c][o] = w1[o][c]
  __shared__ float wl2[C1][C2];     // wl2[c][o] = w2[o][c]
  __shared__ float sb1[2][C1];
  __shared__ float sb2[2][C2];
  __shared__ float xs[35][S];
  __shared__ float o1s[C1][S];
  __shared__ float pm[256];

  const int tid = threadIdx.x;
  for (int i = tid; i < 35 * C1; i += 256) {
    int o = i % C1, c = i / C1;
    wl1[c][o] = w1[o * 35 + c];
  }
  for (int i = tid; i < C1 * C2; i += 256) {
    int o = i % C2, c = i / C2;
    wl2[c][o] = w2[o * C1 + c];
  }
  if (tid < C1) { sb1[0][tid] = s1[tid]; sb1[1][tid] = b1[tid]; }
  if (tid < C2) { sb2[0][tid] = s2[tid]; sb2[1][tid] = b2[tid]; }

  const int b  = blockIdx.x / (P / 8);
  const int p0 = (blockIdx.x % (P / 8)) * 8;
  const float* xb = xyz + (size_t)b * (N * 3);
  const float* fb = feats + (size_t)b * (C_IN * N);
  __syncthreads();

  for (int pi = 0; pi < 8; ++pi) {
    const int p = p0 + pi;
    const size_t bp = (size_t)b * P + p;
    const int* ip = idx + bp * S;
    const float cx = new_xyz[bp * 3 + 0];
    const float cy = new_xyz[bp * 3 + 1];
    const float cz = new_xyz[bp * 3 + 2];
    // gather grouped input (35, S): xyz-diff channels 0..2, features 3..34
    for (int i = tid; i < 35 * S; i += 256) {
      int c = i / S, s = i % S;
      int n = ip[s];
      float v;
      if (c == 0)      v = xb[n * 3 + 0] - cx;
      else if (c == 1) v = xb[n * 3 + 1] - cy;
      else if (c == 2) v = xb[n * 3 + 2] - cz;
      else             v = fb[(size_t)(c - 3) * N + n];
      xs[c][s] = v;
    }
    __syncthreads();
    // layer 1: out1[o][s] = relu(dot(w1[o], x[:,s]) * s1[o] + b1[o])
    {
      constexpr int OPT = (C1 * S) / 256;
      const int s  = tid % S;
      const int ob = (tid / S) * OPT;
      float acc[OPT];
#pragma unroll
      for (int j = 0; j < OPT; ++j) acc[j] = 0.0f;
      for (int c = 0; c < 35; ++c) {
        float xv = xs[c][s];
#pragma unroll
        for (int j = 0; j < OPT; ++j) acc[j] = fmaf(xv, wl1[c][ob + j], acc[j]);
      }
#pragma unroll
      for (int j = 0; j < OPT; ++j) {
        float v = fmaf(acc[j], sb1[0][ob + j], sb1[1][ob + j]);
        o1s[ob + j][s] = fmaxf(v, 0.0f);
      }
    }
    __syncthreads();
    // layer 2 + max over s
    {
      constexpr int NS = (C2 * S) / 256;
      const int o2 = tid % C2;
      const int sb = (tid / C2) * NS;
      float acc[NS];
#pragma unroll
      for (int j = 0; j < NS; ++j) acc[j] = 0.0f;
      for (int c = 0; c < C1; ++c) {
        float wv = wl2[c][o2];
#pragma unroll
        for (int j = 0; j < NS; ++j) acc[j] = fmaf(wv, o1s[c][sb + j], acc[j]);
      }
      const float scale = sb2[0][o2], bias = sb2[1][o2];
      float m = 0.0f;  // relu floor: max over relu(v) == max(0, max v)
#pragma unroll
      for (int j = 0; j < NS; ++j) {
        float v = fmaf(acc[j], scale, bias);
        m = fmaxf(m, v);
      }
      pm[tid] = m;
      __syncthreads();
      if (tid < C2) {
        float mm = pm[tid];
#pragma unroll
        for (int g = 1; g < 256 / C2; ++g) mm = fmaxf(mm, pm[tid + g * C2]);
        out[((size_t)b * 192 + CH_OFF + tid) * P + p] = mm;
      }
    }
    __syncthreads();
  }
}

extern "C" void kernel_launch(void* const* d_in, const int* in_sizes, int n_in,
                              void* d_out, int out_size, void* d_ws, size_t ws_size,
                              hipStream_t stream) {
  const float* xyz   = (const float*)d_in[0];
  const float* feats = (const float*)d_in[1];
  const float* w0_0 = (const float*)d_in[2];
  const float* s0_0 = (const float*)d_in[3];
  const float* b0_0 = (const float*)d_in[4];
  const float* w0_1 = (const float*)d_in[5];
  const float* s0_1 = (const float*)d_in[6];
  const float* b0_1 = (const float*)d_in[7];
  const float* w1_0 = (const float*)d_in[8];
  const float* s1_0 = (const float*)d_in[9];
  const float* b1_0 = (const float*)d_in[10];
  const float* w1_1 = (const float*)d_in[11];
  const float* s1_1 = (const float*)d_in[12];
  const float* b1_1 = (const float*)d_in[13];

  float* out      = (float*)d_out;
  float* new_xyz  = out;                 // (B,P,3)
  float* feat_out = out + (size_t)B * P * 3;  // (B,192,P)

  char* w = (char*)d_ws;
  int* idx0 = (int*)w; w += (size_t)B * P * 16 * sizeof(int);
  int* idx1 = (int*)w; w += (size_t)B * P * 32 * sizeof(int);

  fps_kernel<<<dim3(B), dim3(1024), 0, stream>>>(xyz, new_xyz);
  ballq_kernel<<<dim3(B * P / 4), dim3(256), 0, stream>>>(xyz, new_xyz, idx0, idx1);
  mlp_kernel<16, 32, 64, 0><<<dim3(B * P / 8), dim3(256), 0, stream>>>(
      xyz, feats, new_xyz, idx0, w0_0, s0_0, b0_0, w0_1, s0_1, b0_1, feat_out);
  mlp_kernel<32, 64, 128, 64><<<dim3(B * P / 8), dim3(256), 0, stream>>>(
      xyz, feats, new_xyz, idx1, w1_0, s1_0, b1_0, w1_1, s1_1, b1_1, feat_out);
}

// Round 5
// 2302.716 us; speedup vs baseline: 1.2439x; 1.2439x over previous
//
#include <hip/hip_runtime.h>

#define B 8
#define N 16384
#define C_IN 32
#define P 1024

// ---------------------------------------------------------------------------
// FPS: one block per batch, 1024 threads, 16 points/thread.
// R5: R4 proved dur tracks VALU instruction count (VALUBusy 90% of active
// CUs). Cut instructions: (1) value-only wave max (4 DPP fmax + 2 bpermute)
// instead of (val,idx,z) triple-carry; (2) cross-wave reduce replaced by ONE
// LDS ds_min_u64 with order-encoding key
//     key = (P-1-iter)<<46 | ~bits(val)<<14 | n
// val>=0 so float bits are monotone: min key == (max val, then min n) ==
// numpy first-max EXACTLY (ties included). Decreasing iter-prefix => keys
// strictly decrease across iterations => no re-init; parity slots make
// read/atomic epochs barrier-separated => ONE __syncthreads per iteration.
// (3) no z-carry: cz via uniform scalar load, overlapped with LDS broadcast.
// Data layout (from R3): x,y in LDS (float2, 2-lane bank alias = free),
// z + dmin in regs. Distance math bitwise-matches numpy:
// d = ((dx*dx + dy*dy) + dz*dz), no fma; dmin = fminf.
// ---------------------------------------------------------------------------
#define R16(OP) OP(0) OP(1) OP(2) OP(3) OP(4) OP(5) OP(6) OP(7) \
                OP(8) OP(9) OP(10) OP(11) OP(12) OP(13) OP(14) OP(15)
#define G0(OP) OP(0) OP(1) OP(2) OP(3)
#define G1(OP) OP(4) OP(5) OP(6) OP(7)
#define G2(OP) OP(8) OP(9) OP(10) OP(11)
#define G3(OP) OP(12) OP(13) OP(14) OP(15)

// one max-reduce level via DPP (xor1/xor2/xor4/xor8 patterns)
template <int CTRL>
__device__ __forceinline__ float dpp_fmax(float v) {
  float o = __int_as_float(__builtin_amdgcn_update_dpp(
      __float_as_int(v), __float_as_int(v), CTRL, 0xF, 0xF, false));
  return fmaxf(v, o);
}

__global__ __launch_bounds__(1024)
void fps_kernel(const float* __restrict__ xyz, float* __restrict__ new_xyz)
{
  __shared__ float2 sxy[N];                  // 128 KiB: x,y of every point
  __shared__ unsigned long long slot[2];     // argmax key, parity-alternating

  const int b = blockIdx.x;
  const int t = threadIdx.x;
  const float* xb = xyz + (size_t)b * (N * 3);

  if (t == 0) { slot[0] = ~0ull; slot[1] = ~0ull; }

#define FPS_DECL(i) float pz##i, dm##i = 1e10f;
  R16(FPS_DECL)
#define FPS_LOAD(i) { const int n = t + (i << 10);                             \
    float x = xb[n * 3 + 0];                                                   \
    float y = xb[n * 3 + 1];                                                   \
    pz##i   = xb[n * 3 + 2];                                                   \
    asm volatile("" : "+v"(pz##i));  /* keep z in a VGPR, no remat/reload */   \
    sxy[n] = make_float2(x, y); }
  R16(FPS_LOAD)

  // bpermute lane selectors for the xor16 / xor32 reduce levels
  const int bpa16 = ((t & 63) ^ 16) << 2;
  const int bpa32 = ((t & 63) ^ 32) << 2;

  float cz = xb[2];                 // z of point 0
  __syncthreads();
  float2 c0 = sxy[0];
  float cx = c0.x, cy = c0.y;
  float mx = 0.f, my = 0.f, mz = 0.f;   // this thread's captured centroid

  for (int iter = 0; iter < P; ++iter) {
    // thread `iter` captures the centroid; all stores happen after the loop
    bool keep = (t == iter);
    mx = keep ? cx : mx;
    my = keep ? cy : my;
    mz = keep ? cz : mz;
    if (iter == P - 1) break;

    float bestv = -1.0f;
    int   bi = 0;
    // n = t + (i<<10) ascends with i, so strict '>' keeps the smallest i.
#define FPS_PRE(i) float2 q##i = sxy[t + (i << 10)];
#define FPS_CALC(i) {                                                          \
    float dx = __fsub_rn(q##i.x, cx);                                          \
    float dy = __fsub_rn(q##i.y, cy);                                          \
    float dz = __fsub_rn(pz##i, cz);                                           \
    float d  = __fadd_rn(__fadd_rn(__fmul_rn(dx, dx), __fmul_rn(dy, dy)),      \
                         __fmul_rn(dz, dz));                                   \
    dm##i = fminf(dm##i, d);                                                   \
    bool better = dm##i > bestv;                                               \
    bestv = better ? dm##i : bestv;                                            \
    bi    = better ? i      : bi; }
    { G0(FPS_PRE) G0(FPS_CALC) }
    { G1(FPS_PRE) G1(FPS_CALC) }
    { G2(FPS_PRE) G2(FPS_CALC) }
    { G3(FPS_PRE) G3(FPS_CALC) }

    // value-only wave max: 4 DPP levels + bpermute xor16 + bpermute xor32
    float wm = bestv;
    wm = dpp_fmax<0xB1>(wm);    // quad_perm xor1
    wm = dpp_fmax<0x4E>(wm);    // quad_perm xor2
    wm = dpp_fmax<0x141>(wm);   // row_half_mirror (xor4)
    wm = dpp_fmax<0x140>(wm);   // row_mirror (xor8)
    wm = fmaxf(wm, __int_as_float(
        __builtin_amdgcn_ds_bpermute(bpa16, __float_as_int(wm))));
    wm = fmaxf(wm, __int_as_float(
        __builtin_amdgcn_ds_bpermute(bpa32, __float_as_int(wm))));

    // candidates (>=1 lane/wave) race via order-encoding key; min key wins.
    if (bestv == wm) {
      unsigned nn  = (unsigned)(t + (bi << 10));             // 14 bits
      unsigned inv = ~__float_as_uint(bestv);                // desc in val
      unsigned long long key =
          ((unsigned long long)(unsigned)(P - 1 - iter) << 46) |
          ((unsigned long long)inv << 14) |
          (unsigned long long)nn;
      atomicMin(&slot[iter & 1], key);
    }
    __syncthreads();

    unsigned long long k = slot[iter & 1];
    int sel = __builtin_amdgcn_readfirstlane((int)((unsigned)k & 0x3FFFu));
    float2 nxy = sxy[sel];          // uniform addr -> LDS broadcast
    cx = nxy.x;
    cy = nxy.y;
    cz = xb[sel * 3 + 2];           // uniform scalar load, overlaps broadcast
  }

  // thread t holds the centroid of iteration t
  {
    size_t o = ((size_t)b * P + t) * 3;
    new_xyz[o + 0] = mx;
    new_xyz[o + 1] = my;
    new_xyz[o + 2] = mz;
  }
#undef FPS_DECL
#undef FPS_LOAD
#undef FPS_PRE
#undef FPS_CALC
}

// ---------------------------------------------------------------------------
// Ball query, both radii in one pass. One wave per (b,p). Reproduces the
// reference's gemm-form dist2 bitwise: (qq + xx) - 2*((cx*x+cy*y)+cz*z).
// First-nsample-in-index-order via ballot + prefix popcount; pad = first hit.
// ---------------------------------------------------------------------------
__global__ __launch_bounds__(256) void ballq_kernel(
    const float* __restrict__ xyz, const float* __restrict__ new_xyz,
    int* __restrict__ idx0, int* __restrict__ idx1)
{
  const int wid  = blockIdx.x * 4 + (threadIdx.x >> 6);
  const int lane = threadIdx.x & 63;
  const int b = wid >> 10;
  const int p = wid & (P - 1);
  const float* xb = xyz + (size_t)b * (N * 3);
  const size_t bp = (size_t)b * P + p;
  const float cx = new_xyz[bp * 3 + 0];
  const float cy = new_xyz[bp * 3 + 1];
  const float cz = new_xyz[bp * 3 + 2];
  const float qv = __fadd_rn(__fadd_rn(__fmul_rn(cx, cx), __fmul_rn(cy, cy)),
                             __fmul_rn(cz, cz));
  int* __restrict__ o0 = idx0 + bp * 16;
  int* __restrict__ o1 = idx1 + bp * 32;

  int c0 = 0, c1 = 0, f0 = 0, f1 = 0;
  const unsigned long long below = (1ull << lane) - 1ull;

  for (int base = 0; base < N; base += 64) {
    int n = base + lane;
    float x = xb[n * 3 + 0], y = xb[n * 3 + 1], z = xb[n * 3 + 2];
    float xxv = __fadd_rn(__fadd_rn(__fmul_rn(x, x), __fmul_rn(y, y)),
                          __fmul_rn(z, z));
    float dot = __fadd_rn(__fadd_rn(__fmul_rn(cx, x), __fmul_rn(cy, y)),
                          __fmul_rn(cz, z));
    float d2 = __fsub_rn(__fadd_rn(qv, xxv), __fmul_rn(2.0f, dot));
    unsigned long long m0 = __ballot(d2 < 0.25f);
    unsigned long long m1 = __ballot(d2 < 1.0f);
    if (c0 == 0 && m0) f0 = base + __builtin_ctzll(m0);
    if (c1 == 0 && m1) f1 = base + __builtin_ctzll(m1);
    if ((m0 >> lane) & 1ull) {
      int pos = c0 + (int)__builtin_popcountll(m0 & below);
      if (pos < 16) o0[pos] = n;
    }
    if ((m1 >> lane) & 1ull) {
      int pos = c1 + (int)__builtin_popcountll(m1 & below);
      if (pos < 32) o1[pos] = n;
    }
    c0 = min(16, c0 + (int)__builtin_popcountll(m0));
    c1 = min(32, c1 + (int)__builtin_popcountll(m1));
    if (c0 >= 16 && c1 >= 32) break;
  }
  for (int s = c0 + lane; s < 16; s += 64) o0[s] = f0;
  for (int s = c1 + lane; s < 32; s += 64) o1[s] = f1;
}

// ---------------------------------------------------------------------------
// Fused grouping + conv1(+BN+ReLU) + conv2(+BN+ReLU) + max over samples.
// Block = 256 threads handles 8 points; weights staged in LDS once per block.
// out layout: (B, 192, P) at d_out + B*P*3, branch writes CH_OFF..CH_OFF+C2.
// ---------------------------------------------------------------------------
template <int S, int C1, int C2, int CH_OFF>
__global__ __launch_bounds__(256) void mlp_kernel(
    const float* __restrict__ xyz, const float* __restrict__ feats,
    const float* __restrict__ new_xyz, const int* __restrict__ idx,
    const float* __restrict__ w1, const float* __restrict__ s1,
    const float* __restrict__ b1, const float* __restrict__ w2,
    const float* __restrict__ s2, const float* __restrict__ b2,
    float* __restrict__ out)
{
  static_assert((C1 * S) % 256 == 0 && (C2 * S) % 256 == 0, "mapping");
  __shared__ float wl1[35][C1];     // wl1[c][o] = w1[o][c]
  __shared__ float wl2[C1][C2];     // wl2[c][o] = w2[o][c]
  __shared__ float sb1[2][C1];
  __shared__ float sb2[2][C2];
  __shared__ float xs[35][S];
  __shared__ float o1s[C1][S];
  __shared__ float pm[256];

  const int tid = threadIdx.x;
  for (int i = tid; i < 35 * C1; i += 256) {
    int o = i % C1, c = i / C1;
    wl1[c][o] = w1[o * 35 + c];
  }
  for (int i = tid; i < C1 * C2; i += 256) {
    int o = i % C2, c = i / C2;
    wl2[c][o] = w2[o * C1 + c];
  }
  if (tid < C1) { sb1[0][tid] = s1[tid]; sb1[1][tid] = b1[tid]; }
  if (tid < C2) { sb2[0][tid] = s2[tid]; sb2[1][tid] = b2[tid]; }

  const int b  = blockIdx.x / (P / 8);
  const int p0 = (blockIdx.x % (P / 8)) * 8;
  const float* xb = xyz + (size_t)b * (N * 3);
  const float* fb = feats + (size_t)b * (C_IN * N);
  __syncthreads();

  for (int pi = 0; pi < 8; ++pi) {
    const int p = p0 + pi;
    const size_t bp = (size_t)b * P + p;
    const int* ip = idx + bp * S;
    const float cx = new_xyz[bp * 3 + 0];
    const float cy = new_xyz[bp * 3 + 1];
    const float cz = new_xyz[bp * 3 + 2];
    // gather grouped input (35, S): xyz-diff channels 0..2, features 3..34
    for (int i = tid; i < 35 * S; i += 256) {
      int c = i / S, s = i % S;
      int n = ip[s];
      float v;
      if (c == 0)      v = xb[n * 3 + 0] - cx;
      else if (c == 1) v = xb[n * 3 + 1] - cy;
      else if (c == 2) v = xb[n * 3 + 2] - cz;
      else             v = fb[(size_t)(c - 3) * N + n];
      xs[c][s] = v;
    }
    __syncthreads();
    // layer 1: out1[o][s] = relu(dot(w1[o], x[:,s]) * s1[o] + b1[o])
    {
      constexpr int OPT = (C1 * S) / 256;
      const int s  = tid % S;
      const int ob = (tid / S) * OPT;
      float acc[OPT];
#pragma unroll
      for (int j = 0; j < OPT; ++j) acc[j] = 0.0f;
      for (int c = 0; c < 35; ++c) {
        float xv = xs[c][s];
#pragma unroll
        for (int j = 0; j < OPT; ++j) acc[j] = fmaf(xv, wl1[c][ob + j], acc[j]);
      }
#pragma unroll
      for (int j = 0; j < OPT; ++j) {
        float v = fmaf(acc[j], sb1[0][ob + j], sb1[1][ob + j]);
        o1s[ob + j][s] = fmaxf(v, 0.0f);
      }
    }
    __syncthreads();
    // layer 2 + max over s
    {
      constexpr int NS = (C2 * S) / 256;
      const int o2 = tid % C2;
      const int sb = (tid / C2) * NS;
      float acc[NS];
#pragma unroll
      for (int j = 0; j < NS; ++j) acc[j] = 0.0f;
      for (int c = 0; c < C1; ++c) {
        float wv = wl2[c][o2];
#pragma unroll
        for (int j = 0; j < NS; ++j) acc[j] = fmaf(wv, o1s[c][sb + j], acc[j]);
      }
      const float scale = sb2[0][o2], bias = sb2[1][o2];
      float m = 0.0f;  // relu floor: max over relu(v) == max(0, max v)
#pragma unroll
      for (int j = 0; j < NS; ++j) {
        float v = fmaf(acc[j], scale, bias);
        m = fmaxf(m, v);
      }
      pm[tid] = m;
      __syncthreads();
      if (tid < C2) {
        float mm = pm[tid];
#pragma unroll
        for (int g = 1; g < 256 / C2; ++g) mm = fmaxf(mm, pm[tid + g * C2]);
        out[((size_t)b * 192 + CH_OFF + tid) * P + p] = mm;
      }
    }
    __syncthreads();
  }
}

extern "C" void kernel_launch(void* const* d_in, const int* in_sizes, int n_in,
                              void* d_out, int out_size, void* d_ws, size_t ws_size,
                              hipStream_t stream) {
  const float* xyz   = (const float*)d_in[0];
  const float* feats = (const float*)d_in[1];
  const float* w0_0 = (const float*)d_in[2];
  const float* s0_0 = (const float*)d_in[3];
  const float* b0_0 = (const float*)d_in[4];
  const float* w0_1 = (const float*)d_in[5];
  const float* s0_1 = (const float*)d_in[6];
  const float* b0_1 = (const float*)d_in[7];
  const float* w1_0 = (const float*)d_in[8];
  const float* s1_0 = (const float*)d_in[9];
  const float* b1_0 = (const float*)d_in[10];
  const float* w1_1 = (const float*)d_in[11];
  const float* s1_1 = (const float*)d_in[12];
  const float* b1_1 = (const float*)d_in[13];

  float* out      = (float*)d_out;
  float* new_xyz  = out;                 // (B,P,3)
  float* feat_out = out + (size_t)B * P * 3;  // (B,192,P)

  char* w = (char*)d_ws;
  int* idx0 = (int*)w; w += (size_t)B * P * 16 * sizeof(int);
  int* idx1 = (int*)w; w += (size_t)B * P * 32 * sizeof(int);

  fps_kernel<<<dim3(B), dim3(1024), 0, stream>>>(xyz, new_xyz);
  ballq_kernel<<<dim3(B * P / 4), dim3(256), 0, stream>>>(xyz, new_xyz, idx0, idx1);
  mlp_kernel<16, 32, 64, 0><<<dim3(B * P / 8), dim3(256), 0, stream>>>(
      xyz, feats, new_xyz, idx0, w0_0, s0_0, b0_0, w0_1, s0_1, b0_1, feat_out);
  mlp_kernel<32, 64, 128, 64><<<dim3(B * P / 8), dim3(256), 0, stream>>>(
      xyz, feats, new_xyz, idx1, w1_0, s1_0, b1_0, w1_1, s1_1, b1_1, feat_out);
}